// Round 3
// baseline (164.577 us; speedup 1.0000x reference)
//
#include <hip/hip_runtime.h>

#define T_SEQ 2048
#define C_DIM 128
#define S_QK 0.08838834764831845f

typedef __attribute__((ext_vector_type(8))) short bf16x8;
typedef __attribute__((ext_vector_type(4))) float f32x4;

// ---- workspace layout ----
// qw  bf16 [8][2048][128]   @ 0
// kw  bf16 [8][2048][128]   @ 4,194,304
// vw  bf16 [8][128][2048]   @ 8,388,608  (V^T)
// opart bf16 [1120][64][128] @ 12,582,912  (18,350,080 B)
// ml  float2 [1120][64]      @ 30,932,992  (573,440 B)   total ~31.5 MB
#define ML_OFF 30932992UL

__device__ __forceinline__ unsigned short f2bf(float f) {
    union { float f; unsigned int u; } v; v.f = f;
    unsigned int r = v.u + 0x7FFFu + ((v.u >> 16) & 1u);
    return (unsigned short)(r >> 16);
}
__device__ __forceinline__ float bf2f(unsigned short s) {
    union { unsigned int u; float f; } v; v.u = ((unsigned int)s) << 16;
    return v.f;
}

// slot base within a batch for qt>=4, chunks of 4 key-tiles (140 slots/batch)
__device__ __forceinline__ int chunk_base4(int qt) {
    int g = qt >> 2;                       // 1..7
    return 2 * (g - 1) * (g + 2) + (qt - 4 * g) * (g + 1);
}

// ---------------------------------------------------------------------------
// proj: one of q|k|vT = x @ W^T, fp32->bf16 conversion fused into staging.
// grid (256 row-tiles, 3), block 256.
// ---------------------------------------------------------------------------
__global__ __launch_bounds__(256) void proj_kernel(
    const float* __restrict__ x,
    const float* __restrict__ Wq, const float* __restrict__ Wk,
    const float* __restrict__ Wv,
    unsigned short* __restrict__ qo, unsigned short* __restrict__ ko,
    unsigned short* __restrict__ vto)
{
    const int rt = blockIdx.x;             // 64-row tile over B*T
    const int z  = blockIdx.y;             // 0=q, 1=k, 2=v(transposed)
    const int tid  = threadIdx.x;
    const int lane = tid & 63;
    const int w    = tid >> 6;
    const int n16  = lane & 15;
    const int quad = lane >> 4;

    __shared__ __align__(16) unsigned short Wl[128 * 136];   // 34816 B
    __shared__ __align__(16) unsigned short Xl[9216];        // 18432 B

    const float* W = (z == 0) ? Wq : (z == 1) ? Wk : Wv;
    const float scale = (z == 0) ? S_QK : 1.0f;   // fold C^-0.5 into Wq

    #pragma unroll
    for (int i = 0; i < 16; ++i) {
        int e = (tid + i * 256) * 4;       // 16384 W elements
        int r = e >> 7, c = e & 127;
        float4 v = *reinterpret_cast<const float4*>(W + e);
        ushort4 o4;
        o4.x = f2bf(v.x * scale); o4.y = f2bf(v.y * scale);
        o4.z = f2bf(v.z * scale); o4.w = f2bf(v.w * scale);
        *reinterpret_cast<ushort4*>(&Wl[r * 136 + c]) = o4;
    }
    const float* xr = x + (size_t)rt * 64 * C_DIM;
    #pragma unroll
    for (int i = 0; i < 8; ++i) {
        int e = (tid + i * 256) * 4;       // 8192 x elements
        int r = e >> 7, c = e & 127;
        float4 v = *reinterpret_cast<const float4*>(xr + e);
        ushort4 o4;
        o4.x = f2bf(v.x); o4.y = f2bf(v.y); o4.z = f2bf(v.z); o4.w = f2bf(v.w);
        *reinterpret_cast<ushort4*>(&Xl[r * 136 + c]) = o4;
    }
    __syncthreads();

    const int arow = w * 16 + n16;
    bf16x8 afr[4];
    #pragma unroll
    for (int kk = 0; kk < 4; ++kk)
        afr[kk] = *reinterpret_cast<const bf16x8*>(&Xl[arow * 136 + kk * 32 + quad * 8]);

    f32x4 acc[8];
    #pragma unroll
    for (int nt = 0; nt < 8; ++nt) acc[nt] = (f32x4){0.f, 0.f, 0.f, 0.f};
    #pragma unroll
    for (int kk = 0; kk < 4; ++kk)
        #pragma unroll
        for (int nt = 0; nt < 8; ++nt) {
            bf16x8 bfr = *reinterpret_cast<const bf16x8*>(
                &Wl[(nt * 16 + n16) * 136 + kk * 32 + quad * 8]);
            acc[nt] = __builtin_amdgcn_mfma_f32_16x16x32_bf16(afr[kk], bfr, acc[nt], 0, 0, 0);
        }

    const int trow_base = w * 16 + quad * 4;
    __syncthreads();                       // all waves done reading Xl
    if (z < 2) {
        #pragma unroll
        for (int nt = 0; nt < 8; ++nt)
            #pragma unroll
            for (int r = 0; r < 4; ++r)
                Xl[(trow_base + r) * 136 + nt * 16 + n16] = f2bf(acc[nt][r]);
        __syncthreads();
        unsigned short* dst = (z == 0 ? qo : ko) + (size_t)rt * 64 * C_DIM;
        #pragma unroll
        for (int i = 0; i < 4; ++i) {
            int e = (tid + i * 256) * 8;
            int r = e >> 7, c = e & 127;
            *reinterpret_cast<uint4*>(dst + e) =
                *reinterpret_cast<const uint4*>(&Xl[r * 136 + c]);
        }
    } else {
        const int b  = rt >> 5;
        const int qt = rt & 31;
        #pragma unroll
        for (int nt = 0; nt < 8; ++nt)
            #pragma unroll
            for (int r = 0; r < 4; ++r)
                Xl[(nt * 16 + n16) * 72 + trow_base + r] = f2bf(acc[nt][r]);
        __syncthreads();
        unsigned short* dst = vto + (size_t)b * C_DIM * T_SEQ + (size_t)qt * 64;
        #pragma unroll
        for (int i = 0; i < 4; ++i) {
            int e = tid + i * 256;
            int d = e >> 3, cv = (e & 7) * 8;
            *reinterpret_cast<uint4*>(dst + (size_t)d * T_SEQ + cv) =
                *reinterpret_cast<const uint4*>(&Xl[d * 72 + cv]);
        }
    }
}

// ---------------------------------------------------------------------------
// attn pass 1: split-K flash attention, register-prefetched K/V staging.
// grid (32 qtiles, 8 chunks, 8 batch), chunk = 4 key-tiles.
// qt<4: single chunk writes final output; else bf16 partial O + (m,l).
// ---------------------------------------------------------------------------
__global__ __launch_bounds__(256) void attn_kernel(
    const unsigned short* __restrict__ qb,
    const unsigned short* __restrict__ kb,
    const unsigned short* __restrict__ vtb,
    unsigned short* __restrict__ opart, float2* __restrict__ mlbuf,
    float* __restrict__ out)
{
    const int qt    = blockIdx.x;
    const int chunk = blockIdx.y;
    const int b     = blockIdx.z;
    if (chunk * 4 > qt) return;

    const int tid  = threadIdx.x;
    const int lane = tid & 63;
    const int w    = tid >> 6;
    const int n16  = lane & 15;
    const int quad = lane >> 4;

    __shared__ __align__(16) unsigned short Kl[64 * 136];    // 17408 B
    __shared__ __align__(16) unsigned short Vl[128 * 72];    // 18432 B
    __shared__ __align__(16) unsigned short Pl[4][16 * 72];  //  9216 B

    const size_t bT = (size_t)b * T_SEQ;
    const int qbase = qt * 64 + w * 16;

    bf16x8 qfr[4];
    #pragma unroll
    for (int kk = 0; kk < 4; ++kk)
        qfr[kk] = *reinterpret_cast<const bf16x8*>(
            qb + (bT + qbase + n16) * C_DIM + kk * 32 + quad * 8);

    f32x4 o[8];
    #pragma unroll
    for (int ct = 0; ct < 8; ++ct) o[ct] = (f32x4){0.f, 0.f, 0.f, 0.f};
    float m[4], l[4];
    #pragma unroll
    for (int r = 0; r < 4; ++r) { m[r] = -INFINITY; l[r] = 0.f; }

    const int k0 = chunk * 4;
    const int k1 = min(k0 + 4, qt + 1);

    // ---- prologue: load tile k0 into registers ----
    uint4 kreg[4], vreg[4];
    {
        const unsigned short* ks = kb + (bT + (size_t)k0 * 64) * C_DIM;
        #pragma unroll
        for (int i = 0; i < 4; ++i) {
            int e = tid + i * 256;
            kreg[i] = *reinterpret_cast<const uint4*>(ks + (e >> 4) * 128 + (e & 15) * 8);
        }
        const unsigned short* vs = vtb + (size_t)b * C_DIM * T_SEQ + (size_t)k0 * 64;
        #pragma unroll
        for (int i = 0; i < 4; ++i) {
            int e = tid + i * 256;
            vreg[i] = *reinterpret_cast<const uint4*>(vs + (size_t)(e >> 3) * T_SEQ + (e & 7) * 8);
        }
    }

    for (int kt = k0; kt < k1; ++kt) {
        __syncthreads();                   // prev iteration's LDS reads done
        #pragma unroll
        for (int i = 0; i < 4; ++i) {
            int e = tid + i * 256;
            *reinterpret_cast<uint4*>(&Kl[(e >> 4) * 136 + (e & 15) * 8]) = kreg[i];
        }
        #pragma unroll
        for (int i = 0; i < 4; ++i) {
            int e = tid + i * 256;
            *reinterpret_cast<uint4*>(&Vl[(e >> 3) * 72 + (e & 7) * 8]) = vreg[i];
        }
        __syncthreads();

        // ---- prefetch next tile into registers (covered by compute below) ----
        if (kt + 1 < k1) {
            const unsigned short* ks = kb + (bT + (size_t)(kt + 1) * 64) * C_DIM;
            #pragma unroll
            for (int i = 0; i < 4; ++i) {
                int e = tid + i * 256;
                kreg[i] = *reinterpret_cast<const uint4*>(ks + (e >> 4) * 128 + (e & 15) * 8);
            }
            const unsigned short* vs = vtb + (size_t)b * C_DIM * T_SEQ + (size_t)(kt + 1) * 64;
            #pragma unroll
            for (int i = 0; i < 4; ++i) {
                int e = tid + i * 256;
                vreg[i] = *reinterpret_cast<const uint4*>(vs + (size_t)(e >> 3) * T_SEQ + (e & 7) * 8);
            }
        }

        // ---- S = Q K^T ----
        f32x4 s[4];
        #pragma unroll
        for (int nt = 0; nt < 4; ++nt) s[nt] = (f32x4){0.f, 0.f, 0.f, 0.f};
        #pragma unroll
        for (int kk = 0; kk < 4; ++kk)
            #pragma unroll
            for (int nt = 0; nt < 4; ++nt) {
                bf16x8 bfr = *reinterpret_cast<const bf16x8*>(
                    &Kl[(nt * 16 + n16) * 136 + kk * 32 + quad * 8]);
                s[nt] = __builtin_amdgcn_mfma_f32_16x16x32_bf16(qfr[kk], bfr, s[nt], 0, 0, 0);
            }

        if (kt == qt) {                    // causal mask, diagonal tile only
            #pragma unroll
            for (int nt = 0; nt < 4; ++nt)
                #pragma unroll
                for (int r = 0; r < 4; ++r) {
                    int sabs = kt * 64 + nt * 16 + n16;
                    int qabs = qbase + quad * 4 + r;
                    if (sabs > qabs) s[nt][r] = -1e30f;
                }
        }

        // ---- online softmax ----
        float alpha[4];
        #pragma unroll
        for (int r = 0; r < 4; ++r) {
            float tmax = fmaxf(fmaxf(s[0][r], s[1][r]), fmaxf(s[2][r], s[3][r]));
            #pragma unroll
            for (int off = 1; off < 16; off <<= 1)
                tmax = fmaxf(tmax, __shfl_xor(tmax, off));
            float mn = fmaxf(m[r], tmax);
            alpha[r] = __expf(m[r] - mn);
            float tsum = 0.f;
            #pragma unroll
            for (int nt = 0; nt < 4; ++nt) {
                float p = __expf(s[nt][r] - mn);
                s[nt][r] = p;
                tsum += p;
            }
            #pragma unroll
            for (int off = 1; off < 16; off <<= 1)
                tsum += __shfl_xor(tsum, off);
            l[r] = l[r] * alpha[r] + tsum;
            m[r] = mn;
        }
        #pragma unroll
        for (int ct = 0; ct < 8; ++ct)
            #pragma unroll
            for (int r = 0; r < 4; ++r)
                o[ct][r] *= alpha[r];

        // ---- P: C-layout -> per-wave LDS -> A-layout ----
        unsigned short* pw = Pl[w];
        #pragma unroll
        for (int nt = 0; nt < 4; ++nt)
            #pragma unroll
            for (int r = 0; r < 4; ++r)
                pw[(quad * 4 + r) * 72 + nt * 16 + n16] = f2bf(s[nt][r]);

        // ---- O += P V ----
        #pragma unroll
        for (int kk2 = 0; kk2 < 2; ++kk2) {
            bf16x8 afr = *reinterpret_cast<const bf16x8*>(
                &pw[n16 * 72 + kk2 * 32 + quad * 8]);
            #pragma unroll
            for (int ct = 0; ct < 8; ++ct) {
                bf16x8 bfr = *reinterpret_cast<const bf16x8*>(
                    &Vl[(ct * 16 + n16) * 72 + kk2 * 32 + quad * 8]);
                o[ct] = __builtin_amdgcn_mfma_f32_16x16x32_bf16(afr, bfr, o[ct], 0, 0, 0);
            }
        }
    }

    if (qt < 4) {
        float* outp = out + (bT + qbase) * C_DIM;
        #pragma unroll
        for (int r = 0; r < 4; ++r) {
            float inv = 1.0f / l[r];
            #pragma unroll
            for (int ct = 0; ct < 8; ++ct)
                outp[(size_t)(quad * 4 + r) * C_DIM + ct * 16 + n16] = o[ct][r] * inv;
        }
    } else {
        const int slot = b * 140 + chunk_base4(qt) + chunk;
        unsigned short* op = opart + (size_t)slot * 8192;
        #pragma unroll
        for (int r = 0; r < 4; ++r) {
            int row = w * 16 + quad * 4 + r;
            #pragma unroll
            for (int ct = 0; ct < 8; ++ct)
                op[row * 128 + ct * 16 + n16] = f2bf(o[ct][r]);
            if (n16 == 0)
                mlbuf[(size_t)slot * 64 + row] = make_float2(m[r], l[r]);
        }
    }
}

// ---------------------------------------------------------------------------
// merge: combine <=8 bf16 partials per (b, qt>=4). grid (28, 8), block 256.
// ---------------------------------------------------------------------------
__global__ __launch_bounds__(256) void merge_kernel(
    const unsigned short* __restrict__ opart, const float2* __restrict__ mlbuf,
    float* __restrict__ out)
{
    const int qt = 4 + blockIdx.x;
    const int b  = blockIdx.y;
    const int nch  = (qt >> 2) + 1;
    const int base = b * 140 + chunk_base4(qt);
    const int row = threadIdx.x >> 2;
    const int c0  = (threadIdx.x & 3) * 32;

    float mi[8], li[8], wgt[8];
    float M = -INFINITY;
    for (int i = 0; i < nch; ++i) {
        float2 t = mlbuf[(size_t)(base + i) * 64 + row];
        mi[i] = t.x; li[i] = t.y;
        M = fmaxf(M, t.x);
    }
    float L = 0.f;
    for (int i = 0; i < nch; ++i) {
        wgt[i] = __expf(mi[i] - M);
        L += li[i] * wgt[i];
    }
    const float inv = 1.0f / L;

    float acc[32];
    #pragma unroll
    for (int j = 0; j < 32; ++j) acc[j] = 0.f;
    for (int i = 0; i < nch; ++i) {
        const unsigned short* op = opart + (size_t)(base + i) * 8192 + row * 128 + c0;
        const float wg = wgt[i];
        #pragma unroll
        for (int j4 = 0; j4 < 4; ++j4) {
            uint4 u = *reinterpret_cast<const uint4*>(op + j4 * 8);
            unsigned int vals[4] = {u.x, u.y, u.z, u.w};
            #pragma unroll
            for (int h = 0; h < 4; ++h) {
                union { unsigned int u; float f; } lo, hi;
                lo.u = (vals[h] & 0xFFFFu) << 16;
                hi.u = vals[h] & 0xFFFF0000u;
                acc[j4 * 8 + h * 2]     += wg * lo.f;
                acc[j4 * 8 + h * 2 + 1] += wg * hi.f;
            }
        }
    }
    float* orow = out + ((size_t)(b * T_SEQ + qt * 64 + row)) * C_DIM + c0;
    #pragma unroll
    for (int j4 = 0; j4 < 8; ++j4) {
        float4 r4;
        r4.x = acc[j4 * 4]     * inv;
        r4.y = acc[j4 * 4 + 1] * inv;
        r4.z = acc[j4 * 4 + 2] * inv;
        r4.w = acc[j4 * 4 + 3] * inv;
        *reinterpret_cast<float4*>(orow + j4 * 4) = r4;
    }
}

extern "C" void kernel_launch(void* const* d_in, const int* in_sizes, int n_in,
                              void* d_out, int out_size, void* d_ws, size_t ws_size,
                              hipStream_t stream) {
    const float* x  = (const float*)d_in[0];
    const float* Wk = (const float*)d_in[1];
    const float* Wq = (const float*)d_in[2];
    const float* Wv = (const float*)d_in[3];

    unsigned short* qw    = (unsigned short*)d_ws;
    unsigned short* kw    = qw + 2097152;
    unsigned short* vw    = kw + 2097152;
    unsigned short* opart = vw + 2097152;
    float2*         mlb   = (float2*)((char*)d_ws + ML_OFF);

    proj_kernel<<<dim3(256, 3), 256, 0, stream>>>(x, Wq, Wk, Wv, qw, kw, vw);
    attn_kernel<<<dim3(32, 8, 8), 256, 0, stream>>>(qw, kw, vw, opart, mlb, (float*)d_out);
    merge_kernel<<<dim3(28, 8), 256, 0, stream>>>(opart, mlb, (float*)d_out);
}